// Round 7
// baseline (339.867 us; speedup 1.0000x reference)
//
#include <hip/hip_runtime.h>
#include <cstdint>
#include <cstddef>

typedef __bf16 bf16_t;
typedef __bf16 bf16x8 __attribute__((ext_vector_type(8)));
typedef float  f32x4  __attribute__((ext_vector_type(4)));
typedef unsigned int uint32x4 __attribute__((ext_vector_type(4)));
typedef unsigned int uint32x2 __attribute__((ext_vector_type(2)));

#define DEV_INLINE __device__ __forceinline__

constexpr int Bsz = 4, Ssz = 2048, HID = 1024, FAC = 256, NH = 16, DKc = 64;
constexpr int Mrows = Bsz * Ssz; // 8192
constexpr float QSCALE = 0.18033688011112042f; // (1/sqrt(64)) * log2(e)

struct Ptr8 { const float* p[8]; };
struct Ptr3 { const float* p[3]; };

DEV_INLINE float fast_exp2(float x) {
#if __has_builtin(__builtin_amdgcn_exp2f)
  return __builtin_amdgcn_exp2f(x);
#else
  return exp2f(x);
#endif
}

// async global->LDS, 16 B per lane. LDS dest is wave-uniform base + lane*16.
DEV_INLINE void async16(const void* g, void* l) {
  __builtin_amdgcn_global_load_lds((const __attribute__((address_space(1))) void*)g,
                                   (__attribute__((address_space(3))) void*)l, 16, 0, 0);
}

// Counted-vmcnt barrier: wait until only the N newest VMEM ops remain in flight,
// drain LDS ops (for ds_write visibility), then RAW barrier (no implicit drain).
#define WBAR(N) do { \
  asm volatile("s_waitcnt vmcnt(" #N ") lgkmcnt(0)" ::: "memory"); \
  __builtin_amdgcn_s_barrier(); \
} while (0)

// bank swizzle for [64][64] bf16 tiles staged by global_load_lds:
// LDS[row][c'] holds logical col16 (c' ^ SW(row)). Readers XOR too.
DEV_INLINE int SW(int r) { return (r & 3) | ((r >> 1) & 4); }

// ---------------- prep: weight transpose+cast (z<8) + bias/mask pack (z==8) ----------------
__global__ __launch_bounds__(256) void k_prep(Ptr8 w, Ptr8 bsrc, const int* __restrict__ mask,
                                              bf16_t* wpt, bf16_t* wtt,
                                              float* bp, float* bt, float* mf, bf16_t* mb) {
  const int z = blockIdx.z;
  if (z == 8) {
    const int bid = blockIdx.y * 32 + blockIdx.x;
    if (bid >= 64) return;
    const int i = bid * 256 + threadIdx.x; // 0..16383
    if (i < 4 * FAC) bp[i] = bsrc.p[i >> 8][i & 255];
    if (i < 4 * HID) bt[i] = bsrc.p[4 + (i >> 10)][i & 1023];
    if (i < Bsz * Ssz) {
      const float m = (mask[i] != 0) ? 1.f : 0.f;
      mf[i] = m;
      mb[i] = (bf16_t)m;
    }
    return;
  }
  const int K = (z < 4) ? HID : FAC;
  const int N = (z < 4) ? FAC : HID;
  if ((int)(blockIdx.x * 32) >= N || (int)(blockIdx.y * 32) >= K) return;
  __shared__ float t[32][33];
  const float* src = w.p[z];
  bf16_t* dst = (z < 4) ? (wpt + (size_t)z * FAC * HID) : (wtt + (size_t)(z - 4) * FAC * HID);
  const int tx = threadIdx.x & 31, ty = threadIdx.x >> 5;
  const int kb = blockIdx.y * 32, nb = blockIdx.x * 32;
#pragma unroll
  for (int j = 0; j < 4; ++j)
    t[ty + j * 8][tx] = src[(size_t)(kb + ty + j * 8) * N + nb + tx];
  __syncthreads();
#pragma unroll
  for (int j = 0; j < 4; ++j)
    dst[(size_t)(nb + ty + j * 8) * K + kb + tx] = (bf16_t)t[tx][ty + j * 8];
}

// ---------------- proj GEMM (qkv): C[M,256] = leaky(A_f32[M,1024] @ Bt[256,1024]^T + bias) ----------------
// 64x128 tile, 4 waves, BK=32, nk=32. Counted-vmcnt pipeline.
// launch_bounds(256,3): 3 blocks/CU (LDS 48KB allows it; was VGPR-capped at 2) -> more TLP
// to fill residual per-iter latency.
__global__ __launch_bounds__(256, 3) void k_gemmP2(Ptr3 Asrc,
                                                   const bf16_t* __restrict__ Bt_,
                                                   const float* __restrict__ biasAll,
                                                   bf16_t* __restrict__ Call) {
  __shared__ __align__(16) bf16_t As[3][64 * 40];
  __shared__ __align__(16) bf16_t Bs[4][128 * 32];

  const int z = blockIdx.z;
  const bf16_t* Bt = Bt_ + (size_t)z * FAC * HID;
  const float* bias = biasAll + z * FAC;
  bf16_t* C = Call + (size_t)z * Mrows * FAC;

  const int tid = threadIdx.x;
  const int lane = tid & 63, wave = tid >> 6;
  const int quad = lane >> 4, l16 = lane & 15;
  const int m0 = blockIdx.y * 64, n0 = blockIdx.x * 128;

  const int brow = wave * 16 + (lane >> 2), bkc = (lane & 3) * 8;
  const bf16_t* gB0 = Bt + (size_t)(n0 + brow) * HID + bkc;
  const bf16_t* gB1 = gB0 + (size_t)64 * HID;

  const int crow = tid >> 2, chalf = (tid & 3) * 8;
  const float* gAf = Asrc.p[z] + (size_t)(m0 + crow) * HID + chalf;

#define ASYNCB(t, buf)                                \
  do {                                                \
    const int k0_ = (t) * 32;                         \
    async16(gB0 + k0_, Bs[buf] + wave * 512);         \
    async16(gB1 + k0_, Bs[buf] + 2048 + wave * 512);  \
  } while (0)

  // prologue: A(0) regs first, then B(0),B(1) asyncs, then A(0) LDS write.
  {
    f32x4 pa = *(const f32x4*)gAf;
    f32x4 pb = *(const f32x4*)(gAf + 4);
    __builtin_amdgcn_sched_barrier(0);
    ASYNCB(0, 0);
    ASYNCB(1, 1);
    union { bf16_t h[8]; uint32x4 u; } o;
#pragma unroll
    for (int j = 0; j < 4; ++j) { o.h[j] = (bf16_t)pa[j]; o.h[4 + j] = (bf16_t)pb[j]; }
    *(uint32x4*)(As[0] + crow * 40 + chalf) = o.u;
  }

  f32x4 acc[4][2] = {};
  constexpr int nk = 32;

  for (int it = 0; it < nk; ++it) {
    f32x4 xa, xb;
    const int k1 = (it + 1) * 32;
    if (it + 1 < nk) {
      xa = *(const f32x4*)(gAf + k1);
      xb = *(const f32x4*)(gAf + k1 + 4);
    }
    __builtin_amdgcn_sched_barrier(0);
    if (it + 2 < nk) ASYNCB(it + 2, (it + 2) & 3);

    if (it + 2 < nk)      WBAR(6);
    else if (it + 1 < nk) WBAR(4);
    else                  WBAR(0);

    const bf16_t* Ac = As[it % 3];
    const bf16_t* Bc = Bs[it & 3];
    bf16x8 af[4], bfr[2];
#pragma unroll
    for (int i = 0; i < 4; ++i)
      af[i] = *(const bf16x8*)(Ac + (i * 16 + l16) * 40 + quad * 8);
#pragma unroll
    for (int i = 0; i < 2; ++i)
      bfr[i] = *(const bf16x8*)(Bc + (wave * 32 + i * 16 + l16) * 32 + quad * 8);
#pragma unroll
    for (int mi = 0; mi < 4; ++mi)
#pragma unroll
      for (int ni = 0; ni < 2; ++ni)
        acc[mi][ni] = __builtin_amdgcn_mfma_f32_16x16x32_bf16(af[mi], bfr[ni], acc[mi][ni], 0, 0, 0);

    if (it + 1 < nk) {
      union { bf16_t h[8]; uint32x4 u; } o;
#pragma unroll
      for (int j = 0; j < 4; ++j) { o.h[j] = (bf16_t)xa[j]; o.h[4 + j] = (bf16_t)xb[j]; }
      *(uint32x4*)(As[(it + 1) % 3] + crow * 40 + chalf) = o.u;
    }
  }
#undef ASYNCB

#pragma unroll
  for (int mi = 0; mi < 4; ++mi) {
    const int rbase = m0 + mi * 16 + quad * 4;
#pragma unroll
    for (int ni = 0; ni < 2; ++ni) {
      const int col = n0 + wave * 32 + ni * 16 + l16;
      const float bv = bias[col];
#pragma unroll
      for (int r = 0; r < 4; ++r) {
        float y = acc[mi][ni][r] + bv;
        y = (y > 0.f) ? y : 0.2f * y;
        C[(size_t)(rbase + r) * FAC + col] = (bf16_t)y;
      }
    }
  }
}

// ---------------- deep-pipelined GEMM: C[M,N] = f(A[M,K] @ Bt[N,K]^T + bias) ----------------
// 128x128 tile, 4 waves (each 64x64), BK=32, ring-5 buffers, prefetch DISTANCE 3
// (covers ~900cy HBM latency at ~250cy/iter; D=2 only covered ~500 -> per-iter stall).
// Safety: R=5 >= D+2 (stage(it+3)->buf[(it-2)%5], last read at iter it-2, drained by
// barrier#(it-1) which all waves passed before the stage issues).
// WBAR: 4 async16/stage; steady-state outstanding after issuing stage(it+3) = stages
// it..it+3 (16); retire stage(it) -> WBAR(12). Tail: 8/4/0.
// EPI: 1 = tran-qkv (z0 QSCALE, z1 1.0, z2 mask+transpose into C2 [b,h,d,s]); 2 = fp32 out.
template <int EPI, typename OUT_T>
__global__ __launch_bounds__(256, 2) void k_gemmQ(const bf16_t* __restrict__ Aall,
                                                  const bf16_t* __restrict__ Btall,
                                                  const float* __restrict__ biasAll,
                                                  OUT_T* __restrict__ Call,
                                                  bf16_t* __restrict__ C2,
                                                  const float* __restrict__ rowmul,
                                                  int N, int K,
                                                  long long Az, long long Bz, long long Cz, int biasz) {
  __shared__ __align__(16) bf16_t As[5][128 * 32];
  __shared__ __align__(16) bf16_t Bs[5][128 * 32];

  const int z = blockIdx.z;
  const bf16_t* Bt = Btall + (size_t)z * Bz;
  const float* bias = biasAll + (size_t)z * biasz;
  OUT_T* C = Call + (size_t)z * Cz;

  const int tid = threadIdx.x;
  const int lane = tid & 63, wave = tid >> 6;
  const int quad = lane >> 4, l16 = lane & 15;
  const int wr = wave >> 1, wc = wave & 1;
  const int m0 = blockIdx.y * 128, n0 = blockIdx.x * 128;

  const int arow = wave * 16 + (lane >> 2), akc = (lane & 3) * 8;
  const bf16_t* gB0 = Bt + (size_t)(n0 + arow) * K + akc;
  const bf16_t* gB1 = gB0 + (size_t)64 * K;
  const bf16_t* A = Aall + (size_t)z * Az;
  const bf16_t* gA0 = A + (size_t)(m0 + arow) * K + akc;
  const bf16_t* gA1 = gA0 + (size_t)64 * K;

#define STAGEQ(t, buf)                               \
  do {                                               \
    const int k0_ = (t) * 32;                        \
    async16(gA0 + k0_, As[buf] + wave * 512);        \
    async16(gA1 + k0_, As[buf] + 2048 + wave * 512); \
    async16(gB0 + k0_, Bs[buf] + wave * 512);        \
    async16(gB1 + k0_, Bs[buf] + 2048 + wave * 512); \
  } while (0)

  const int nk = K / 32;
  STAGEQ(0, 0);
  STAGEQ(1, 1);
  STAGEQ(2, 2);

  f32x4 acc[4][4] = {};

  for (int it = 0; it < nk; ++it) {
    if (it + 3 < nk) STAGEQ(it + 3, (it + 3) % 5);

    if (it + 3 < nk)      WBAR(12);
    else if (it + 2 < nk) WBAR(8);
    else if (it + 1 < nk) WBAR(4);
    else                  WBAR(0);

    const bf16_t* Ac = As[it % 5];
    const bf16_t* Bc = Bs[it % 5];
    bf16x8 af[4], bfr[4];
#pragma unroll
    for (int i = 0; i < 4; ++i)
      af[i] = *(const bf16x8*)(Ac + (wr * 64 + i * 16 + l16) * 32 + quad * 8);
#pragma unroll
    for (int i = 0; i < 4; ++i)
      bfr[i] = *(const bf16x8*)(Bc + (wc * 64 + i * 16 + l16) * 32 + quad * 8);
#pragma unroll
    for (int mi = 0; mi < 4; ++mi)
#pragma unroll
      for (int ni = 0; ni < 4; ++ni)
        acc[mi][ni] = __builtin_amdgcn_mfma_f32_16x16x32_bf16(af[mi], bfr[ni], acc[mi][ni], 0, 0, 0);
  }
#undef STAGEQ

  if (EPI == 1 && z == 2) {
    // transposed masked write: V^T[(b*NH+h)*64+d][s] = (acc + bias) * mask[s]
#pragma unroll
    for (int mi = 0; mi < 4; ++mi) {
      const int rbase = m0 + wr * 64 + mi * 16 + quad * 4;
      const int bb = rbase >> 11, s = rbase & 2047;
      float rmv[4];
#pragma unroll
      for (int r = 0; r < 4; ++r) rmv[r] = rowmul[rbase + r];
#pragma unroll
      for (int ni = 0; ni < 4; ++ni) {
        const int col = n0 + wc * 64 + ni * 16 + l16;
        const float bv = bias[col];
        const int hh = col >> 6, d = col & 63;
        union { bf16_t e[4]; uint32x2 u; } p;
#pragma unroll
        for (int r = 0; r < 4; ++r) p.e[r] = (bf16_t)((acc[mi][ni][r] + bv) * rmv[r]);
        *(uint32x2*)(C2 + (((size_t)((bb * NH + hh) * DKc + d)) << 11) + s) = p.u;
      }
    }
    return;
  }

  const float scale = (EPI == 1 && z == 0) ? QSCALE : 1.f;
#pragma unroll
  for (int mi = 0; mi < 4; ++mi) {
    const int rbase = m0 + wr * 64 + mi * 16 + quad * 4;
#pragma unroll
    for (int ni = 0; ni < 4; ++ni) {
      const int col = n0 + wc * 64 + ni * 16 + l16;
      const float bv = bias[col];
#pragma unroll
      for (int r = 0; r < 4; ++r) {
        float y = (acc[mi][ni][r] + bv) * scale;
        C[(size_t)(rbase + r) * N + col] = (OUT_T)y;
      }
    }
  }
}

// ---------------- proj-o GEMM: 64x64 tile, 2 waves, ring-5 D=3 ----------------
// Replaces the 128-block k_gemmQ launch that left HALF the GPU idle: grid = (N/64=4,
// M/64=128) = 512 blocks, LDS 40KB -> 4 blocks/CU. Same counted-vmcnt schedule as k_gemmQ.
__global__ __launch_bounds__(128, 2) void k_gemmO(const bf16_t* __restrict__ A,
                                                  const bf16_t* __restrict__ Bt,
                                                  const float* __restrict__ bias,
                                                  bf16_t* __restrict__ C) {
  __shared__ __align__(16) bf16_t As[5][64 * 32];
  __shared__ __align__(16) bf16_t Bs[5][64 * 32];

  const int tid = threadIdx.x;
  const int lane = tid & 63, wave = tid >> 6; // 0..1
  const int quad = lane >> 4, l16 = lane & 15;
  const int m0 = blockIdx.y * 64, n0 = blockIdx.x * 64;

  const int srow = wave * 32 + (lane >> 2), skc = (lane & 3) * 8;
  const bf16_t* gA0 = A + (size_t)(m0 + srow) * HID + skc;
  const bf16_t* gA1 = gA0 + (size_t)16 * HID;
  const bf16_t* gB0 = Bt + (size_t)(n0 + srow) * HID + skc;
  const bf16_t* gB1 = gB0 + (size_t)16 * HID;

#define STAGEO(t, buf)                                 \
  do {                                                 \
    const int k0_ = (t) * 32;                          \
    async16(gA0 + k0_, As[buf] + wave * 1024);         \
    async16(gA1 + k0_, As[buf] + wave * 1024 + 512);   \
    async16(gB0 + k0_, Bs[buf] + wave * 1024);         \
    async16(gB1 + k0_, Bs[buf] + wave * 1024 + 512);   \
  } while (0)

  constexpr int nk = HID / 32; // 32
  STAGEO(0, 0);
  STAGEO(1, 1);
  STAGEO(2, 2);

  f32x4 acc[4][2] = {};

  for (int it = 0; it < nk; ++it) {
    if (it + 3 < nk) STAGEO(it + 3, (it + 3) % 5);

    if (it + 3 < nk)      WBAR(12);
    else if (it + 2 < nk) WBAR(8);
    else if (it + 1 < nk) WBAR(4);
    else                  WBAR(0);

    const bf16_t* Ac = As[it % 5];
    const bf16_t* Bc = Bs[it % 5];
    bf16x8 af[4], bfr[2];
#pragma unroll
    for (int i = 0; i < 4; ++i)
      af[i] = *(const bf16x8*)(Ac + (i * 16 + l16) * 32 + quad * 8);
#pragma unroll
    for (int i = 0; i < 2; ++i)
      bfr[i] = *(const bf16x8*)(Bc + (wave * 32 + i * 16 + l16) * 32 + quad * 8);
#pragma unroll
    for (int mi = 0; mi < 4; ++mi)
#pragma unroll
      for (int ni = 0; ni < 2; ++ni)
        acc[mi][ni] = __builtin_amdgcn_mfma_f32_16x16x32_bf16(af[mi], bfr[ni], acc[mi][ni], 0, 0, 0);
  }
#undef STAGEO

#pragma unroll
  for (int mi = 0; mi < 4; ++mi) {
    const int rbase = m0 + mi * 16 + quad * 4;
#pragma unroll
    for (int ni = 0; ni < 2; ++ni) {
      const int col = n0 + wave * 32 + ni * 16 + l16;
      const float bv = bias[col];
#pragma unroll
      for (int r = 0; r < 4; ++r) {
        float y = acc[mi][ni][r] + bv;
        y = (y > 0.f) ? y : 0.2f * y;
        C[(size_t)(rbase + r) * FAC + col] = (bf16_t)y;
      }
    }
  }
}

// ---------------- flash attention v9b: 512 q-rows/block, 8 waves x 4 q-groups ----------------
// At the 2-barrier structure ceiling (~830 TF). Added: s_setprio(1) around dacc+PV MFMA
// cluster (T5) — counted-vmcnt phases give wave role-diversity for the scheduler.
__global__ __launch_bounds__(512, 2) void k_attn(const bf16_t* __restrict__ qkv,
                                                 const bf16_t* __restrict__ mb,
                                                 bf16_t* __restrict__ cv) {
  __shared__ __align__(16) bf16_t Ks[4][64 * 64];
  __shared__ __align__(16) bf16_t Vt[4][64 * 64];
  __shared__ __align__(16) bf16_t Ml[Ssz];

  const int qt = blockIdx.x, h = blockIdx.y, b = blockIdx.z;
  const bf16_t* qp = qkv;
  const bf16_t* kp = qkv + (size_t)Mrows * HID;
  const bf16_t* vtp = qkv + 2 * (size_t)Mrows * HID + (size_t)(b * NH + h) * DKc * Ssz;

  const int tid = threadIdx.x;
  const int lane = tid & 63, wave = tid >> 6;   // wave 0..7
  const int quad = lane >> 4, l16 = lane & 15;

  // staging: each of 8 waves stages 8 rows of K and 8 rows of V^T (1024 B each)
  const int r0 = wave * 8 + (lane >> 3);
  const int c0 = ((lane & 7) ^ SW(r0)) * 8;
  const int ldsOff = wave * 512; // elements (1024 B per wave)
  const bf16_t* kgA = kp + (size_t)(b * Ssz + r0) * HID + h * DKc + c0;
  const bf16_t* vgA = vtp + (size_t)r0 * Ssz + c0;

#define STAGEA(t, buf)                                          \
  do {                                                          \
    async16(kgA + (size_t)(t) * 64 * HID, Ks[buf] + ldsOff);    \
    async16(vgA + (t) * 64, Vt[buf] + ldsOff);                  \
  } while (0)

  *(uint32x2*)(Ml + tid * 4) = *(const uint32x2*)(mb + (size_t)b * Ssz + tid * 4);
  STAGEA(0, 0);
  STAGEA(1, 1);

  // 4 q-groups of 16 rows per wave: rows qt*512 + g*128 + wave*16 + l16
  bf16x8 aq0[4], aq1[4];
#pragma unroll
  for (int g = 0; g < 4; ++g) {
    const size_t qrow = (size_t)(b * Ssz + qt * 512 + g * 128 + wave * 16 + l16) * HID + h * DKc + quad * 8;
    aq0[g] = *(const bf16x8*)(qp + qrow);
    aq1[g] = *(const bf16x8*)(qp + qrow + 32);
  }

  const int krow = 8 * (l16 >> 2) + (l16 & 3);
  f32x4 acc[4][4] = {};
  f32x4 dacc[4] = {};
  const bf16x8 zfrag = {};

  for (int kt = 0; kt < 32; ++kt) {
    if (kt + 2 < 32) STAGEA(kt + 2, (kt + 2) & 3);

    if (kt + 2 < 32)      WBAR(4);
    else if (kt + 1 < 32) WBAR(2);
    else                  WBAR(0);

    const bf16_t* Kc = Ks[kt & 3];
    const bf16_t* Vc = Vt[kt & 3];

    union U { uint32x4 u; bf16x8 h; } ap0[4], ap1[4];
    constexpr int koff[4] = {0, 4, 32, 36};
#pragma unroll
    for (int ks = 0; ks < 4; ++ks) {
      const int row = krow + koff[ks];
      const int sw = SW(row);
      bf16x8 a0 = *(const bf16x8*)(Kc + row * 64 + (quad ^ sw) * 8);
      bf16x8 a1 = *(const bf16x8*)(Kc + row * 64 + ((quad + 4) ^ sw) * 8);
#pragma unroll
      for (int g = 0; g < 4; ++g) {
        f32x4 c = {};
        c = __builtin_amdgcn_mfma_f32_16x16x32_bf16(a0, aq0[g], c, 0, 0, 0);
        c = __builtin_amdgcn_mfma_f32_16x16x32_bf16(a1, aq1[g], c, 0, 0, 0);
        union { bf16_t h[2]; uint32_t u; } p01, p23;
        p01.h[0] = (bf16_t)fast_exp2(c[0]);
        p01.h[1] = (bf16_t)fast_exp2(c[1]);
        p23.h[0] = (bf16_t)fast_exp2(c[2]);
        p23.h[1] = (bf16_t)fast_exp2(c[3]);
        U& t = (ks < 2) ? ap0[g] : ap1[g];
        t.u[(ks & 1) * 2] = p01.u;
        t.u[(ks & 1) * 2 + 1] = p23.u;
      }
    }

    bf16x8 mr0 = *(const bf16x8*)(Ml + kt * 64 + quad * 8);
    bf16x8 mr1 = *(const bf16x8*)(Ml + kt * 64 + 32 + quad * 8);
    if (l16 != 0) { mr0 = zfrag; mr1 = zfrag; }

    __builtin_amdgcn_s_setprio(1);
#pragma unroll
    for (int g = 0; g < 4; ++g) {
      dacc[g] = __builtin_amdgcn_mfma_f32_16x16x32_bf16(ap0[g].h, mr0, dacc[g], 0, 0, 0);
      dacc[g] = __builtin_amdgcn_mfma_f32_16x16x32_bf16(ap1[g].h, mr1, dacc[g], 0, 0, 0);
    }

#pragma unroll
    for (int d = 0; d < 4; ++d) {
      const int row = d * 16 + l16;
      const int sw = SW(row);
      bf16x8 bv0 = *(const bf16x8*)(Vc + row * 64 + (quad ^ sw) * 8);
      bf16x8 bv1 = *(const bf16x8*)(Vc + row * 64 + ((quad + 4) ^ sw) * 8);
#pragma unroll
      for (int g = 0; g < 4; ++g) {
        acc[g][d] = __builtin_amdgcn_mfma_f32_16x16x32_bf16(ap0[g].h, bv0, acc[g][d], 0, 0, 0);
        acc[g][d] = __builtin_amdgcn_mfma_f32_16x16x32_bf16(ap1[g].h, bv1, acc[g][d], 0, 0, 0);
      }
    }
    __builtin_amdgcn_s_setprio(0);
  }
#undef STAGEA

#pragma unroll
  for (int g = 0; g < 4; ++g) {
    const size_t obase = (size_t)(b * Ssz + qt * 512 + g * 128 + wave * 16 + quad * 4) * HID + h * DKc + l16;
#pragma unroll
    for (int r = 0; r < 4; ++r) {
      const float denom = __shfl(dacc[g][r], lane & 48, 64);
      const float rl = 1.f / denom;
#pragma unroll
      for (int d = 0; d < 4; ++d)
        cv[obase + (size_t)r * HID + d * 16] = (bf16_t)(acc[g][d][r] * rl);
    }
  }
}

// ---------------- host ----------------
extern "C" void kernel_launch(void* const* d_in, const int* in_sizes, int n_in,
                              void* d_out, int out_size, void* d_ws, size_t ws_size,
                              hipStream_t stream) {
  (void)in_sizes; (void)n_in; (void)out_size; (void)ws_size;
  const float* q_in = (const float*)d_in[0];
  const float* k_in = (const float*)d_in[1];
  const float* v_in = (const float*)d_in[2];
  const int* mask = (const int*)d_in[3];

  bf16_t* XB = (bf16_t*)d_ws;                          // 3 slots [8192,1024] bf16: q, k, V^T
  bf16_t* H3 = XB + (size_t)3 * Mrows * HID;           // 3 x [8192,256] bf16
  bf16_t* CV = H3 + (size_t)3 * Mrows * FAC;           // [8192,1024] bf16 (attn out)
  bf16_t* WPT = CV + (size_t)Mrows * HID;              // 4 x [256,1024] bf16
  bf16_t* WTT = WPT + (size_t)4 * FAC * HID;           // 4 x [1024,256] bf16
  float* BP = (float*)(WTT + (size_t)4 * FAC * HID);   // 4 x 256 f32
  float* BT = BP + 4 * FAC;                            // 4 x 1024 f32
  float* MF = BT + 4 * HID;                            // [8192] f32 mask rowmul
  bf16_t* MB = (bf16_t*)(MF + Mrows);                  // [8192] bf16 mask row
  bf16_t* VTg = XB + 2 * (size_t)Mrows * HID;          // V^T slot

  Ptr8 w;
  w.p[0] = (const float*)d_in[4];  w.p[1] = (const float*)d_in[8];
  w.p[2] = (const float*)d_in[12]; w.p[3] = (const float*)d_in[16];
  w.p[4] = (const float*)d_in[6];  w.p[5] = (const float*)d_in[10];
  w.p[6] = (const float*)d_in[14]; w.p[7] = (const float*)d_in[18];
  Ptr8 bs;
  bs.p[0] = (const float*)d_in[5];  bs.p[1] = (const float*)d_in[9];
  bs.p[2] = (const float*)d_in[13]; bs.p[3] = (const float*)d_in[17];
  bs.p[4] = (const float*)d_in[7];  bs.p[5] = (const float*)d_in[11];
  bs.p[6] = (const float*)d_in[15]; bs.p[7] = (const float*)d_in[19];
  hipLaunchKernelGGL(k_prep, dim3(32, 32, 9), dim3(256), 0, stream, w, bs, mask,
                     WPT, WTT, BP, BT, MF, MB);

  Ptr3 xs; xs.p[0] = q_in; xs.p[1] = k_in; xs.p[2] = v_in;

  // proj q,k,v: fp32 A (cast fused) @ WPT^T + b -> leaky -> H3 [3 blocks/CU]
  hipLaunchKernelGGL(k_gemmP2, dim3(2, Mrows / 64, 3), dim3(256), 0, stream,
                     xs, WPT, BP, H3);

  // tran q,k,v: H3 @ WTT^T + b -> q(scaled),k into XB; v masked+TRANSPOSED into VTg [D=3 ring5]
  hipLaunchKernelGGL((k_gemmQ<1, bf16_t>), dim3(HID / 128, Mrows / 128, 3), dim3(256), 0, stream,
                     H3, WTT, BT, XB, VTg, MF,
                     HID, FAC, (long long)Mrows * FAC, (long long)FAC * HID, (long long)Mrows * HID, HID);

  // attention -> CV (512 q-rows per block, 8 waves x 4 groups, 256 blocks)
  hipLaunchKernelGGL(k_attn, dim3(Ssz / 512, NH, Bsz), dim3(512), 0, stream, XB, MB, CV);

  // proj o: CV @ WPT[o]^T + b -> leaky -> H3[0]  [512 blocks, 64x64 tiles, D=3 ring5]
  hipLaunchKernelGGL(k_gemmO, dim3(FAC / 64, Mrows / 64, 1), dim3(128), 0, stream,
                     CV, WPT + (size_t)3 * FAC * HID, BP + 3 * FAC, H3);

  // tran o: H3 @ WTT[o]^T + b -> d_out (fp32)  [512 blocks, D=3 ring5]
  hipLaunchKernelGGL((k_gemmQ<2, float>), dim3(HID / 128, Mrows / 128, 1), dim3(256), 0, stream,
                     H3, WTT + (size_t)3 * FAC * HID, BT + 3 * HID, (float*)d_out, (bf16_t*)nullptr,
                     (const float*)nullptr, HID, FAC, 0LL, 0LL, 0LL, 0);
}

// Round 8
// 336.052 us; speedup vs baseline: 1.0114x; 1.0114x over previous
//
#include <hip/hip_runtime.h>
#include <cstdint>
#include <cstddef>

typedef __bf16 bf16_t;
typedef __bf16 bf16x8 __attribute__((ext_vector_type(8)));
typedef float  f32x4  __attribute__((ext_vector_type(4)));
typedef unsigned int uint32x4 __attribute__((ext_vector_type(4)));
typedef unsigned int uint32x2 __attribute__((ext_vector_type(2)));

#define DEV_INLINE __device__ __forceinline__

constexpr int Bsz = 4, Ssz = 2048, HID = 1024, FAC = 256, NH = 16, DKc = 64;
constexpr int Mrows = Bsz * Ssz; // 8192
constexpr float QSCALE = 0.18033688011112042f; // (1/sqrt(64)) * log2(e)

struct Ptr8 { const float* p[8]; };
struct Ptr3 { const float* p[3]; };

DEV_INLINE float fast_exp2(float x) {
#if __has_builtin(__builtin_amdgcn_exp2f)
  return __builtin_amdgcn_exp2f(x);
#else
  return exp2f(x);
#endif
}

// async global->LDS, 16 B per lane. LDS dest is wave-uniform base + lane*16.
DEV_INLINE void async16(const void* g, void* l) {
  __builtin_amdgcn_global_load_lds((const __attribute__((address_space(1))) void*)g,
                                   (__attribute__((address_space(3))) void*)l, 16, 0, 0);
}

// Counted-vmcnt barrier: wait until only the N newest VMEM ops remain in flight,
// drain LDS ops (for ds_write visibility), then RAW barrier (no implicit drain).
#define WBAR(N) do { \
  asm volatile("s_waitcnt vmcnt(" #N ") lgkmcnt(0)" ::: "memory"); \
  __builtin_amdgcn_s_barrier(); \
} while (0)

// bank swizzle for [64][64] bf16 tiles staged by global_load_lds:
// LDS[row][c'] holds logical col16 (c' ^ SW(row)). Readers XOR too.
DEV_INLINE int SW(int r) { return (r & 3) | ((r >> 1) & 4); }

// ---------------- prep: weight transpose+cast (z<8) + bias/mask pack (z==8) ----------------
// Grid (256,1,9): every block does work (R0..R7 had 9216 blocks, 77% empty).
__global__ __launch_bounds__(256) void k_prep(Ptr8 w, Ptr8 bsrc, const int* __restrict__ mask,
                                              bf16_t* wpt, bf16_t* wtt,
                                              float* bp, float* bt, float* mf, bf16_t* mb) {
  const int z = blockIdx.z;
  if (z == 8) {
    if (blockIdx.x >= 64) return;
    const int i = blockIdx.x * 256 + threadIdx.x; // 0..16383
    if (i < 4 * FAC) bp[i] = bsrc.p[i >> 8][i & 255];
    if (i < 4 * HID) bt[i] = bsrc.p[4 + (i >> 10)][i & 1023];
    if (i < Bsz * Ssz) {
      const float m = (mask[i] != 0) ? 1.f : 0.f;
      mf[i] = m;
      mb[i] = (bf16_t)m;
    }
    return;
  }
  const int K = (z < 4) ? HID : FAC;
  const int N = (z < 4) ? FAC : HID;
  const int nbN = N / 32; // 8 (z<4) or 32
  const int nb = (blockIdx.x % nbN) * 32, kb = (blockIdx.x / nbN) * 32; // 256 blocks exactly
  __shared__ float t[32][33];
  const float* src = w.p[z];
  bf16_t* dst = (z < 4) ? (wpt + (size_t)z * FAC * HID) : (wtt + (size_t)(z - 4) * FAC * HID);
  const int tx = threadIdx.x & 31, ty = threadIdx.x >> 5;
#pragma unroll
  for (int j = 0; j < 4; ++j)
    t[ty + j * 8][tx] = src[(size_t)(kb + ty + j * 8) * N + nb + tx];
  __syncthreads();
#pragma unroll
  for (int j = 0; j < 4; ++j)
    dst[(size_t)(nb + ty + j * 8) * K + kb + tx] = (bf16_t)t[tx][ty + j * 8];
}

// ---------------- proj GEMM (qkv): C[M,256] = leaky(A_f32[M,1024] @ Bt[256,1024]^T + bias) ----------------
// 64x128 tile, 4 waves, BK=32, nk=32. Counted-vmcnt pipeline, 3 blocks/CU.
__global__ __launch_bounds__(256, 3) void k_gemmP2(Ptr3 Asrc,
                                                   const bf16_t* __restrict__ Bt_,
                                                   const float* __restrict__ biasAll,
                                                   bf16_t* __restrict__ Call) {
  __shared__ __align__(16) bf16_t As[3][64 * 40];
  __shared__ __align__(16) bf16_t Bs[4][128 * 32];

  const int z = blockIdx.z;
  const bf16_t* Bt = Bt_ + (size_t)z * FAC * HID;
  const float* bias = biasAll + z * FAC;
  bf16_t* C = Call + (size_t)z * Mrows * FAC;

  const int tid = threadIdx.x;
  const int lane = tid & 63, wave = tid >> 6;
  const int quad = lane >> 4, l16 = lane & 15;
  const int m0 = blockIdx.y * 64, n0 = blockIdx.x * 128;

  const int brow = wave * 16 + (lane >> 2), bkc = (lane & 3) * 8;
  const bf16_t* gB0 = Bt + (size_t)(n0 + brow) * HID + bkc;
  const bf16_t* gB1 = gB0 + (size_t)64 * HID;

  const int crow = tid >> 2, chalf = (tid & 3) * 8;
  const float* gAf = Asrc.p[z] + (size_t)(m0 + crow) * HID + chalf;

#define ASYNCB(t, buf)                                \
  do {                                                \
    const int k0_ = (t) * 32;                         \
    async16(gB0 + k0_, Bs[buf] + wave * 512);         \
    async16(gB1 + k0_, Bs[buf] + 2048 + wave * 512);  \
  } while (0)

  // prologue: A(0) regs first, then B(0),B(1) asyncs, then A(0) LDS write.
  {
    f32x4 pa = *(const f32x4*)gAf;
    f32x4 pb = *(const f32x4*)(gAf + 4);
    __builtin_amdgcn_sched_barrier(0);
    ASYNCB(0, 0);
    ASYNCB(1, 1);
    union { bf16_t h[8]; uint32x4 u; } o;
#pragma unroll
    for (int j = 0; j < 4; ++j) { o.h[j] = (bf16_t)pa[j]; o.h[4 + j] = (bf16_t)pb[j]; }
    *(uint32x4*)(As[0] + crow * 40 + chalf) = o.u;
  }

  f32x4 acc[4][2] = {};
  constexpr int nk = 32;

  for (int it = 0; it < nk; ++it) {
    f32x4 xa, xb;
    const int k1 = (it + 1) * 32;
    if (it + 1 < nk) {
      xa = *(const f32x4*)(gAf + k1);
      xb = *(const f32x4*)(gAf + k1 + 4);
    }
    __builtin_amdgcn_sched_barrier(0);
    if (it + 2 < nk) ASYNCB(it + 2, (it + 2) & 3);

    if (it + 2 < nk)      WBAR(6);
    else if (it + 1 < nk) WBAR(4);
    else                  WBAR(0);

    const bf16_t* Ac = As[it % 3];
    const bf16_t* Bc = Bs[it & 3];
    bf16x8 af[4], bfr[2];
#pragma unroll
    for (int i = 0; i < 4; ++i)
      af[i] = *(const bf16x8*)(Ac + (i * 16 + l16) * 40 + quad * 8);
#pragma unroll
    for (int i = 0; i < 2; ++i)
      bfr[i] = *(const bf16x8*)(Bc + (wave * 32 + i * 16 + l16) * 32 + quad * 8);
#pragma unroll
    for (int mi = 0; mi < 4; ++mi)
#pragma unroll
      for (int ni = 0; ni < 2; ++ni)
        acc[mi][ni] = __builtin_amdgcn_mfma_f32_16x16x32_bf16(af[mi], bfr[ni], acc[mi][ni], 0, 0, 0);

    if (it + 1 < nk) {
      union { bf16_t h[8]; uint32x4 u; } o;
#pragma unroll
      for (int j = 0; j < 4; ++j) { o.h[j] = (bf16_t)xa[j]; o.h[4 + j] = (bf16_t)xb[j]; }
      *(uint32x4*)(As[(it + 1) % 3] + crow * 40 + chalf) = o.u;
    }
  }
#undef ASYNCB

#pragma unroll
  for (int mi = 0; mi < 4; ++mi) {
    const int rbase = m0 + mi * 16 + quad * 4;
#pragma unroll
    for (int ni = 0; ni < 2; ++ni) {
      const int col = n0 + wave * 32 + ni * 16 + l16;
      const float bv = bias[col];
#pragma unroll
      for (int r = 0; r < 4; ++r) {
        float y = acc[mi][ni][r] + bv;
        y = (y > 0.f) ? y : 0.2f * y;
        C[(size_t)(rbase + r) * FAC + col] = (bf16_t)y;
      }
    }
  }
}

// ---------------- deep-pipelined GEMM: C[M,N] = f(A[M,K] @ Bt[N,K]^T + bias) ----------------
// 128x128 tile, 4 waves, BK=32, ring-5, prefetch distance 3, WBAR(12/8/4/0).
// EPI: 1 = tran-qkv (z0 QSCALE, z1 1.0, z2 mask+transpose into C2 [b,h,d,s]); 2 = fp32 out.
template <int EPI, typename OUT_T>
__global__ __launch_bounds__(256, 2) void k_gemmQ(const bf16_t* __restrict__ Aall,
                                                  const bf16_t* __restrict__ Btall,
                                                  const float* __restrict__ biasAll,
                                                  OUT_T* __restrict__ Call,
                                                  bf16_t* __restrict__ C2,
                                                  const float* __restrict__ rowmul,
                                                  int N, int K,
                                                  long long Az, long long Bz, long long Cz, int biasz) {
  __shared__ __align__(16) bf16_t As[5][128 * 32];
  __shared__ __align__(16) bf16_t Bs[5][128 * 32];

  const int z = blockIdx.z;
  const bf16_t* Bt = Btall + (size_t)z * Bz;
  const float* bias = biasAll + (size_t)z * biasz;
  OUT_T* C = Call + (size_t)z * Cz;

  const int tid = threadIdx.x;
  const int lane = tid & 63, wave = tid >> 6;
  const int quad = lane >> 4, l16 = lane & 15;
  const int wr = wave >> 1, wc = wave & 1;
  const int m0 = blockIdx.y * 128, n0 = blockIdx.x * 128;

  const int arow = wave * 16 + (lane >> 2), akc = (lane & 3) * 8;
  const bf16_t* gB0 = Bt + (size_t)(n0 + arow) * K + akc;
  const bf16_t* gB1 = gB0 + (size_t)64 * K;
  const bf16_t* A = Aall + (size_t)z * Az;
  const bf16_t* gA0 = A + (size_t)(m0 + arow) * K + akc;
  const bf16_t* gA1 = gA0 + (size_t)64 * K;

#define STAGEQ(t, buf)                               \
  do {                                               \
    const int k0_ = (t) * 32;                        \
    async16(gA0 + k0_, As[buf] + wave * 512);        \
    async16(gA1 + k0_, As[buf] + 2048 + wave * 512); \
    async16(gB0 + k0_, Bs[buf] + wave * 512);        \
    async16(gB1 + k0_, Bs[buf] + 2048 + wave * 512); \
  } while (0)

  const int nk = K / 32;
  STAGEQ(0, 0);
  STAGEQ(1, 1);
  STAGEQ(2, 2);

  f32x4 acc[4][4] = {};

  for (int it = 0; it < nk; ++it) {
    if (it + 3 < nk) STAGEQ(it + 3, (it + 3) % 5);

    if (it + 3 < nk)      WBAR(12);
    else if (it + 2 < nk) WBAR(8);
    else if (it + 1 < nk) WBAR(4);
    else                  WBAR(0);

    const bf16_t* Ac = As[it % 5];
    const bf16_t* Bc = Bs[it % 5];
    bf16x8 af[4], bfr[4];
#pragma unroll
    for (int i = 0; i < 4; ++i)
      af[i] = *(const bf16x8*)(Ac + (wr * 64 + i * 16 + l16) * 32 + quad * 8);
#pragma unroll
    for (int i = 0; i < 4; ++i)
      bfr[i] = *(const bf16x8*)(Bc + (wc * 64 + i * 16 + l16) * 32 + quad * 8);
#pragma unroll
    for (int mi = 0; mi < 4; ++mi)
#pragma unroll
      for (int ni = 0; ni < 4; ++ni)
        acc[mi][ni] = __builtin_amdgcn_mfma_f32_16x16x32_bf16(af[mi], bfr[ni], acc[mi][ni], 0, 0, 0);
  }
#undef STAGEQ

  if (EPI == 1 && z == 2) {
    // transposed masked write: V^T[(b*NH+h)*64+d][s] = (acc + bias) * mask[s]
#pragma unroll
    for (int mi = 0; mi < 4; ++mi) {
      const int rbase = m0 + wr * 64 + mi * 16 + quad * 4;
      const int bb = rbase >> 11, s = rbase & 2047;
      float rmv[4];
#pragma unroll
      for (int r = 0; r < 4; ++r) rmv[r] = rowmul[rbase + r];
#pragma unroll
      for (int ni = 0; ni < 4; ++ni) {
        const int col = n0 + wc * 64 + ni * 16 + l16;
        const float bv = bias[col];
        const int hh = col >> 6, d = col & 63;
        union { bf16_t e[4]; uint32x2 u; } p;
#pragma unroll
        for (int r = 0; r < 4; ++r) p.e[r] = (bf16_t)((acc[mi][ni][r] + bv) * rmv[r]);
        *(uint32x2*)(C2 + (((size_t)((bb * NH + hh) * DKc + d)) << 11) + s) = p.u;
      }
    }
    return;
  }

  const float scale = (EPI == 1 && z == 0) ? QSCALE : 1.f;
#pragma unroll
  for (int mi = 0; mi < 4; ++mi) {
    const int rbase = m0 + wr * 64 + mi * 16 + quad * 4;
#pragma unroll
    for (int ni = 0; ni < 4; ++ni) {
      const int col = n0 + wc * 64 + ni * 16 + l16;
      const float bv = bias[col];
#pragma unroll
      for (int r = 0; r < 4; ++r) {
        float y = (acc[mi][ni][r] + bv) * scale;
        C[(size_t)(rbase + r) * N + col] = (OUT_T)y;
      }
    }
  }
}

// ---------------- proj-o GEMM: 64x64 tile, 4 waves (wave = 16-row strip), ring-5 D=3 ----------------
// R7's 2-wave version ran at 1 wave/SIMD (no latency hiding). Now: 256 threads, each wave
// computes 16x64 (acc[1][4]), 2 async16/wave/stage, grid 512 -> 2 blocks/CU = 2 waves/SIMD.
// WBAR: 2 async/stage; after issuing stage(it+3): 4 stages in flight = 8 -> WBAR(6). Tail 4/2/0.
__global__ __launch_bounds__(256, 2) void k_gemmO(const bf16_t* __restrict__ A,
                                                  const bf16_t* __restrict__ Bt,
                                                  const float* __restrict__ bias,
                                                  bf16_t* __restrict__ C) {
  __shared__ __align__(16) bf16_t As[5][64 * 32];
  __shared__ __align__(16) bf16_t Bs[5][64 * 32];

  const int tid = threadIdx.x;
  const int lane = tid & 63, wave = tid >> 6; // 0..3
  const int quad = lane >> 4, l16 = lane & 15;
  const int m0 = blockIdx.y * 64, n0 = blockIdx.x * 64;

  const int srow = wave * 16 + (lane >> 2), skc = (lane & 3) * 8;
  const bf16_t* gA0 = A + (size_t)(m0 + srow) * HID + skc;
  const bf16_t* gB0 = Bt + (size_t)(n0 + srow) * HID + skc;

#define STAGEO(t, buf)                                 \
  do {                                                 \
    const int k0_ = (t) * 32;                          \
    async16(gA0 + k0_, As[buf] + wave * 512);          \
    async16(gB0 + k0_, Bs[buf] + wave * 512);          \
  } while (0)

  constexpr int nk = HID / 32; // 32
  STAGEO(0, 0);
  STAGEO(1, 1);
  STAGEO(2, 2);

  f32x4 acc[4] = {};

  for (int it = 0; it < nk; ++it) {
    if (it + 3 < nk) STAGEO(it + 3, (it + 3) % 5);

    if (it + 3 < nk)      WBAR(6);
    else if (it + 2 < nk) WBAR(4);
    else if (it + 1 < nk) WBAR(2);
    else                  WBAR(0);

    const bf16_t* Ac = As[it % 5];
    const bf16_t* Bc = Bs[it % 5];
    bf16x8 af = *(const bf16x8*)(Ac + (wave * 16 + l16) * 32 + quad * 8);
    bf16x8 bfr[4];
#pragma unroll
    for (int i = 0; i < 4; ++i)
      bfr[i] = *(const bf16x8*)(Bc + (i * 16 + l16) * 32 + quad * 8);
#pragma unroll
    for (int ni = 0; ni < 4; ++ni)
      acc[ni] = __builtin_amdgcn_mfma_f32_16x16x32_bf16(af, bfr[ni], acc[ni], 0, 0, 0);
  }
#undef STAGEO

  const int rbase = m0 + wave * 16 + quad * 4;
#pragma unroll
  for (int ni = 0; ni < 4; ++ni) {
    const int col = n0 + ni * 16 + l16;
    const float bv = bias[col];
#pragma unroll
    for (int r = 0; r < 4; ++r) {
      float y = acc[ni][r] + bv;
      y = (y > 0.f) ? y : 0.2f * y;
      C[(size_t)(rbase + r) * FAC + col] = (bf16_t)y;
    }
  }
}

// ---------------- flash attention v9 (R5 exact): 512 q-rows/block, 8 waves x 4 q-groups ----------------
// Known-good 82.9 us. No setprio (R7 measured it -4% here).
__global__ __launch_bounds__(512, 2) void k_attn(const bf16_t* __restrict__ qkv,
                                                 const bf16_t* __restrict__ mb,
                                                 bf16_t* __restrict__ cv) {
  __shared__ __align__(16) bf16_t Ks[4][64 * 64];
  __shared__ __align__(16) bf16_t Vt[4][64 * 64];
  __shared__ __align__(16) bf16_t Ml[Ssz];

  const int qt = blockIdx.x, h = blockIdx.y, b = blockIdx.z;
  const bf16_t* qp = qkv;
  const bf16_t* kp = qkv + (size_t)Mrows * HID;
  const bf16_t* vtp = qkv + 2 * (size_t)Mrows * HID + (size_t)(b * NH + h) * DKc * Ssz;

  const int tid = threadIdx.x;
  const int lane = tid & 63, wave = tid >> 6;   // wave 0..7
  const int quad = lane >> 4, l16 = lane & 15;

  // staging: each of 8 waves stages 8 rows of K and 8 rows of V^T (1024 B each)
  const int r0 = wave * 8 + (lane >> 3);
  const int c0 = ((lane & 7) ^ SW(r0)) * 8;
  const int ldsOff = wave * 512; // elements (1024 B per wave)
  const bf16_t* kgA = kp + (size_t)(b * Ssz + r0) * HID + h * DKc + c0;
  const bf16_t* vgA = vtp + (size_t)r0 * Ssz + c0;

#define STAGEA(t, buf)                                          \
  do {                                                          \
    async16(kgA + (size_t)(t) * 64 * HID, Ks[buf] + ldsOff);    \
    async16(vgA + (t) * 64, Vt[buf] + ldsOff);                  \
  } while (0)

  *(uint32x2*)(Ml + tid * 4) = *(const uint32x2*)(mb + (size_t)b * Ssz + tid * 4);
  STAGEA(0, 0);
  STAGEA(1, 1);

  // 4 q-groups of 16 rows per wave: rows qt*512 + g*128 + wave*16 + l16
  bf16x8 aq0[4], aq1[4];
#pragma unroll
  for (int g = 0; g < 4; ++g) {
    const size_t qrow = (size_t)(b * Ssz + qt * 512 + g * 128 + wave * 16 + l16) * HID + h * DKc + quad * 8;
    aq0[g] = *(const bf16x8*)(qp + qrow);
    aq1[g] = *(const bf16x8*)(qp + qrow + 32);
  }

  const int krow = 8 * (l16 >> 2) + (l16 & 3);
  f32x4 acc[4][4] = {};
  f32x4 dacc[4] = {};
  const bf16x8 zfrag = {};

  for (int kt = 0; kt < 32; ++kt) {
    if (kt + 2 < 32) STAGEA(kt + 2, (kt + 2) & 3);

    if (kt + 2 < 32)      WBAR(4);
    else if (kt + 1 < 32) WBAR(2);
    else                  WBAR(0);

    const bf16_t* Kc = Ks[kt & 3];
    const bf16_t* Vc = Vt[kt & 3];

    union U { uint32x4 u; bf16x8 h; } ap0[4], ap1[4];
    constexpr int koff[4] = {0, 4, 32, 36};
#pragma unroll
    for (int ks = 0; ks < 4; ++ks) {
      const int row = krow + koff[ks];
      const int sw = SW(row);
      bf16x8 a0 = *(const bf16x8*)(Kc + row * 64 + (quad ^ sw) * 8);
      bf16x8 a1 = *(const bf16x8*)(Kc + row * 64 + ((quad + 4) ^ sw) * 8);
#pragma unroll
      for (int g = 0; g < 4; ++g) {
        f32x4 c = {};
        c = __builtin_amdgcn_mfma_f32_16x16x32_bf16(a0, aq0[g], c, 0, 0, 0);
        c = __builtin_amdgcn_mfma_f32_16x16x32_bf16(a1, aq1[g], c, 0, 0, 0);
        union { bf16_t h[2]; uint32_t u; } p01, p23;
        p01.h[0] = (bf16_t)fast_exp2(c[0]);
        p01.h[1] = (bf16_t)fast_exp2(c[1]);
        p23.h[0] = (bf16_t)fast_exp2(c[2]);
        p23.h[1] = (bf16_t)fast_exp2(c[3]);
        U& t = (ks < 2) ? ap0[g] : ap1[g];
        t.u[(ks & 1) * 2] = p01.u;
        t.u[(ks & 1) * 2 + 1] = p23.u;
      }
    }

    bf16x8 mr0 = *(const bf16x8*)(Ml + kt * 64 + quad * 8);
    bf16x8 mr1 = *(const bf16x8*)(Ml + kt * 64 + 32 + quad * 8);
    if (l16 != 0) { mr0 = zfrag; mr1 = zfrag; }
#pragma unroll
    for (int g = 0; g < 4; ++g) {
      dacc[g] = __builtin_amdgcn_mfma_f32_16x16x32_bf16(ap0[g].h, mr0, dacc[g], 0, 0, 0);
      dacc[g] = __builtin_amdgcn_mfma_f32_16x16x32_bf16(ap1[g].h, mr1, dacc[g], 0, 0, 0);
    }

#pragma unroll
    for (int d = 0; d < 4; ++d) {
      const int row = d * 16 + l16;
      const int sw = SW(row);
      bf16x8 bv0 = *(const bf16x8*)(Vc + row * 64 + (quad ^ sw) * 8);
      bf16x8 bv1 = *(const bf16x8*)(Vc + row * 64 + ((quad + 4) ^ sw) * 8);
#pragma unroll
      for (int g = 0; g < 4; ++g) {
        acc[g][d] = __builtin_amdgcn_mfma_f32_16x16x32_bf16(ap0[g].h, bv0, acc[g][d], 0, 0, 0);
        acc[g][d] = __builtin_amdgcn_mfma_f32_16x16x32_bf16(ap1[g].h, bv1, acc[g][d], 0, 0, 0);
      }
    }
  }
#undef STAGEA

#pragma unroll
  for (int g = 0; g < 4; ++g) {
    const size_t obase = (size_t)(b * Ssz + qt * 512 + g * 128 + wave * 16 + quad * 4) * HID + h * DKc + l16;
#pragma unroll
    for (int r = 0; r < 4; ++r) {
      const float denom = __shfl(dacc[g][r], lane & 48, 64);
      const float rl = 1.f / denom;
#pragma unroll
      for (int d = 0; d < 4; ++d)
        cv[obase + (size_t)r * HID + d * 16] = (bf16_t)(acc[g][d][r] * rl);
    }
  }
}

// ---------------- host ----------------
extern "C" void kernel_launch(void* const* d_in, const int* in_sizes, int n_in,
                              void* d_out, int out_size, void* d_ws, size_t ws_size,
                              hipStream_t stream) {
  (void)in_sizes; (void)n_in; (void)out_size; (void)ws_size;
  const float* q_in = (const float*)d_in[0];
  const float* k_in = (const float*)d_in[1];
  const float* v_in = (const float*)d_in[2];
  const int* mask = (const int*)d_in[3];

  bf16_t* XB = (bf16_t*)d_ws;                          // 3 slots [8192,1024] bf16: q, k, V^T
  bf16_t* H3 = XB + (size_t)3 * Mrows * HID;           // 3 x [8192,256] bf16
  bf16_t* CV = H3 + (size_t)3 * Mrows * FAC;           // [8192,1024] bf16 (attn out)
  bf16_t* WPT = CV + (size_t)Mrows * HID;              // 4 x [256,1024] bf16
  bf16_t* WTT = WPT + (size_t)4 * FAC * HID;           // 4 x [1024,256] bf16
  float* BP = (float*)(WTT + (size_t)4 * FAC * HID);   // 4 x 256 f32
  float* BT = BP + 4 * FAC;                            // 4 x 1024 f32
  float* MF = BT + 4 * HID;                            // [8192] f32 mask rowmul
  bf16_t* MB = (bf16_t*)(MF + Mrows);                  // [8192] bf16 mask row
  bf16_t* VTg = XB + 2 * (size_t)Mrows * HID;          // V^T slot

  Ptr8 w;
  w.p[0] = (const float*)d_in[4];  w.p[1] = (const float*)d_in[8];
  w.p[2] = (const float*)d_in[12]; w.p[3] = (const float*)d_in[16];
  w.p[4] = (const float*)d_in[6];  w.p[5] = (const float*)d_in[10];
  w.p[6] = (const float*)d_in[14]; w.p[7] = (const float*)d_in[18];
  Ptr8 bs;
  bs.p[0] = (const float*)d_in[5];  bs.p[1] = (const float*)d_in[9];
  bs.p[2] = (const float*)d_in[13]; bs.p[3] = (const float*)d_in[17];
  bs.p[4] = (const float*)d_in[7];  bs.p[5] = (const float*)d_in[11];
  bs.p[6] = (const float*)d_in[15]; bs.p[7] = (const float*)d_in[19];
  hipLaunchKernelGGL(k_prep, dim3(256, 1, 9), dim3(256), 0, stream, w, bs, mask,
                     WPT, WTT, BP, BT, MF, MB);

  Ptr3 xs; xs.p[0] = q_in; xs.p[1] = k_in; xs.p[2] = v_in;

  // proj q,k,v: fp32 A (cast fused) @ WPT^T + b -> leaky -> H3 [3 blocks/CU]
  hipLaunchKernelGGL(k_gemmP2, dim3(2, Mrows / 64, 3), dim3(256), 0, stream,
                     xs, WPT, BP, H3);

  // tran q,k,v: H3 @ WTT^T + b -> q(scaled),k into XB; v masked+TRANSPOSED into VTg [D=3 ring5]
  hipLaunchKernelGGL((k_gemmQ<1, bf16_t>), dim3(HID / 128, Mrows / 128, 3), dim3(256), 0, stream,
                     H3, WTT, BT, XB, VTg, MF,
                     HID, FAC, (long long)Mrows * FAC, (long long)FAC * HID, (long long)Mrows * HID, HID);

  // attention -> CV (512 q-rows per block, 8 waves x 4 groups, 256 blocks)
  hipLaunchKernelGGL(k_attn, dim3(Ssz / 512, NH, Bsz), dim3(512), 0, stream, XB, MB, CV);

  // proj o: CV @ WPT[o]^T + b -> leaky -> H3[0]  [512 blocks, 4-wave 64x64, D=3 ring5]
  hipLaunchKernelGGL(k_gemmO, dim3(FAC / 64, Mrows / 64, 1), dim3(256), 0, stream,
                     CV, WPT + (size_t)3 * FAC * HID, BP + 3 * FAC, H3);

  // tran o: H3 @ WTT[o]^T + b -> d_out (fp32)  [512 blocks, D=3 ring5]
  hipLaunchKernelGGL((k_gemmQ<2, float>), dim3(HID / 128, Mrows / 128, 1), dim3(256), 0, stream,
                     H3, WTT + (size_t)3 * FAC * HID, BT + 3 * HID, (float*)d_out, (bf16_t*)nullptr,
                     (const float*)nullptr, HID, FAC, 0LL, 0LL, 0LL, 0);
}

// Round 9
// 332.538 us; speedup vs baseline: 1.0220x; 1.0106x over previous
//
#include <hip/hip_runtime.h>
#include <cstdint>
#include <cstddef>

typedef __bf16 bf16_t;
typedef __bf16 bf16x8 __attribute__((ext_vector_type(8)));
typedef float  f32x4  __attribute__((ext_vector_type(4)));
typedef unsigned int uint32x4 __attribute__((ext_vector_type(4)));
typedef unsigned int uint32x2 __attribute__((ext_vector_type(2)));

#define DEV_INLINE __device__ __forceinline__

constexpr int Bsz = 4, Ssz = 2048, HID = 1024, FAC = 256, NH = 16, DKc = 64;
constexpr int Mrows = Bsz * Ssz; // 8192
constexpr float QSCALE = 0.18033688011112042f; // (1/sqrt(64)) * log2(e)

struct Ptr8 { const float* p[8]; };
struct Ptr3 { const float* p[3]; };

DEV_INLINE float fast_exp2(float x) {
#if __has_builtin(__builtin_amdgcn_exp2f)
  return __builtin_amdgcn_exp2f(x);
#else
  return exp2f(x);
#endif
}

// async global->LDS, 16 B per lane. LDS dest is wave-uniform base + lane*16.
DEV_INLINE void async16(const void* g, void* l) {
  __builtin_amdgcn_global_load_lds((const __attribute__((address_space(1))) void*)g,
                                   (__attribute__((address_space(3))) void*)l, 16, 0, 0);
}

// Counted-vmcnt barrier: wait until only the N newest VMEM ops remain in flight,
// drain LDS ops (for ds_write visibility), then RAW barrier (no implicit drain).
#define WBAR(N) do { \
  asm volatile("s_waitcnt vmcnt(" #N ") lgkmcnt(0)" ::: "memory"); \
  __builtin_amdgcn_s_barrier(); \
} while (0)

// bank swizzle for [64][64] bf16 tiles staged by global_load_lds (attn):
// LDS[row][c'] holds logical col16 (c' ^ SW(row)). Readers XOR too.
DEV_INLINE int SW(int r) { return (r & 3) | ((r >> 1) & 4); }

// bank swizzle for [R][32] bf16 tiles (64 B rows): without it, ds_read_b128 at
// (base+l16)*32 + quad*8 puts 8 lanes on one 4-bank span (8-way conflict, ~2.9x).
// LDS slot s of row r holds logical col16 (s ^ SW32(r)); post-swizzle lanes l16 and
// l16+8 share a group -> 2-way = free. SW32(r) = (r>>1)&3 (invariant under r+16/r+64).
DEV_INLINE int SW32(int r) { return (r >> 1) & 3; }

// ---------------- prep: weight transpose+cast (z<8) + bias/mask pack (z==8) ----------------
__global__ __launch_bounds__(256) void k_prep(Ptr8 w, Ptr8 bsrc, const int* __restrict__ mask,
                                              bf16_t* wpt, bf16_t* wtt,
                                              float* bp, float* bt, float* mf, bf16_t* mb) {
  const int z = blockIdx.z;
  if (z == 8) {
    if (blockIdx.x >= 64) return;
    const int i = blockIdx.x * 256 + threadIdx.x; // 0..16383
    if (i < 4 * FAC) bp[i] = bsrc.p[i >> 8][i & 255];
    if (i < 4 * HID) bt[i] = bsrc.p[4 + (i >> 10)][i & 1023];
    if (i < Bsz * Ssz) {
      const float m = (mask[i] != 0) ? 1.f : 0.f;
      mf[i] = m;
      mb[i] = (bf16_t)m;
    }
    return;
  }
  const int K = (z < 4) ? HID : FAC;
  const int N = (z < 4) ? FAC : HID;
  const int nbN = N / 32; // 8 (z<4) or 32
  const int nb = (blockIdx.x % nbN) * 32, kb = (blockIdx.x / nbN) * 32; // 256 blocks exactly
  __shared__ float t[32][33];
  const float* src = w.p[z];
  bf16_t* dst = (z < 4) ? (wpt + (size_t)z * FAC * HID) : (wtt + (size_t)(z - 4) * FAC * HID);
  const int tx = threadIdx.x & 31, ty = threadIdx.x >> 5;
#pragma unroll
  for (int j = 0; j < 4; ++j)
    t[ty + j * 8][tx] = src[(size_t)(kb + ty + j * 8) * N + nb + tx];
  __syncthreads();
#pragma unroll
  for (int j = 0; j < 4; ++j)
    dst[(size_t)(nb + ty + j * 8) * K + kb + tx] = (bf16_t)t[tx][ty + j * 8];
}

// ---------------- proj GEMM (qkv): C[M,256] = leaky(A_f32[M,1024] @ Bt[256,1024]^T + bias) ----------------
// 64x128 tile, 4 waves, BK=32, nk=32. Counted-vmcnt pipeline, 3 blocks/CU.
// B-tile reads now SW32-swizzled (was 8-way bank conflict); A (stride 40) already 2-way-free.
__global__ __launch_bounds__(256, 3) void k_gemmP2(Ptr3 Asrc,
                                                   const bf16_t* __restrict__ Bt_,
                                                   const float* __restrict__ biasAll,
                                                   bf16_t* __restrict__ Call) {
  __shared__ __align__(16) bf16_t As[3][64 * 40];
  __shared__ __align__(16) bf16_t Bs[4][128 * 32];

  const int z = blockIdx.z;
  const bf16_t* Bt = Bt_ + (size_t)z * FAC * HID;
  const float* bias = biasAll + z * FAC;
  bf16_t* C = Call + (size_t)z * Mrows * FAC;

  const int tid = threadIdx.x;
  const int lane = tid & 63, wave = tid >> 6;
  const int quad = lane >> 4, l16 = lane & 15;
  const int swl = SW32(l16);
  const int m0 = blockIdx.y * 64, n0 = blockIdx.x * 128;

  // staging: lane covers LDS slot (lane&3) of row brow; fetch logical col (slot^SW32(brow)).
  const int brow = wave * 16 + (lane >> 2);
  const int bkc = (((lane & 3) ^ SW32(brow)) & 3) * 8;
  const bf16_t* gB0 = Bt + (size_t)(n0 + brow) * HID + bkc;
  const bf16_t* gB1 = gB0 + (size_t)64 * HID;

  const int crow = tid >> 2, chalf = (tid & 3) * 8;
  const float* gAf = Asrc.p[z] + (size_t)(m0 + crow) * HID + chalf;

#define ASYNCB(t, buf)                                \
  do {                                                \
    const int k0_ = (t) * 32;                         \
    async16(gB0 + k0_, Bs[buf] + wave * 512);         \
    async16(gB1 + k0_, Bs[buf] + 2048 + wave * 512);  \
  } while (0)

  // prologue: A(0) regs first, then B(0),B(1) asyncs, then A(0) LDS write.
  {
    f32x4 pa = *(const f32x4*)gAf;
    f32x4 pb = *(const f32x4*)(gAf + 4);
    __builtin_amdgcn_sched_barrier(0);
    ASYNCB(0, 0);
    ASYNCB(1, 1);
    union { bf16_t h[8]; uint32x4 u; } o;
#pragma unroll
    for (int j = 0; j < 4; ++j) { o.h[j] = (bf16_t)pa[j]; o.h[4 + j] = (bf16_t)pb[j]; }
    *(uint32x4*)(As[0] + crow * 40 + chalf) = o.u;
  }

  f32x4 acc[4][2] = {};
  constexpr int nk = 32;

  for (int it = 0; it < nk; ++it) {
    f32x4 xa, xb;
    const int k1 = (it + 1) * 32;
    if (it + 1 < nk) {
      xa = *(const f32x4*)(gAf + k1);
      xb = *(const f32x4*)(gAf + k1 + 4);
    }
    __builtin_amdgcn_sched_barrier(0);
    if (it + 2 < nk) ASYNCB(it + 2, (it + 2) & 3);

    if (it + 2 < nk)      WBAR(6);
    else if (it + 1 < nk) WBAR(4);
    else                  WBAR(0);

    const bf16_t* Ac = As[it % 3];
    const bf16_t* Bc = Bs[it & 3];
    bf16x8 af[4], bfr[2];
#pragma unroll
    for (int i = 0; i < 4; ++i)
      af[i] = *(const bf16x8*)(Ac + (i * 16 + l16) * 40 + quad * 8);
#pragma unroll
    for (int i = 0; i < 2; ++i)
      bfr[i] = *(const bf16x8*)(Bc + (wave * 32 + i * 16 + l16) * 32 + ((quad ^ swl) & 3) * 8);
#pragma unroll
    for (int mi = 0; mi < 4; ++mi)
#pragma unroll
      for (int ni = 0; ni < 2; ++ni)
        acc[mi][ni] = __builtin_amdgcn_mfma_f32_16x16x32_bf16(af[mi], bfr[ni], acc[mi][ni], 0, 0, 0);

    if (it + 1 < nk) {
      union { bf16_t h[8]; uint32x4 u; } o;
#pragma unroll
      for (int j = 0; j < 4; ++j) { o.h[j] = (bf16_t)xa[j]; o.h[4 + j] = (bf16_t)xb[j]; }
      *(uint32x4*)(As[(it + 1) % 3] + crow * 40 + chalf) = o.u;
    }
  }
#undef ASYNCB

#pragma unroll
  for (int mi = 0; mi < 4; ++mi) {
    const int rbase = m0 + mi * 16 + quad * 4;
#pragma unroll
    for (int ni = 0; ni < 2; ++ni) {
      const int col = n0 + wave * 32 + ni * 16 + l16;
      const float bv = bias[col];
#pragma unroll
      for (int r = 0; r < 4; ++r) {
        float y = acc[mi][ni][r] + bv;
        y = (y > 0.f) ? y : 0.2f * y;
        C[(size_t)(rbase + r) * FAC + col] = (bf16_t)y;
      }
    }
  }
}

// ---------------- deep-pipelined GEMM: C[M,N] = f(A[M,K] @ Bt[N,K]^T + bias) ----------------
// 128x128 tile, 4 waves, BK=32, ring-5, prefetch distance 3, WBAR(12/8/4/0).
// A and B tiles SW32-swizzled (pre-swizzled global source; linear async16 dest).
// EPI: 1 = tran-qkv (z0 QSCALE, z1 1.0, z2 mask+transpose into C2 [b,h,d,s]); 2 = fp32 out.
template <int EPI, typename OUT_T>
__global__ __launch_bounds__(256, 2) void k_gemmQ(const bf16_t* __restrict__ Aall,
                                                  const bf16_t* __restrict__ Btall,
                                                  const float* __restrict__ biasAll,
                                                  OUT_T* __restrict__ Call,
                                                  bf16_t* __restrict__ C2,
                                                  const float* __restrict__ rowmul,
                                                  int N, int K,
                                                  long long Az, long long Bz, long long Cz, int biasz) {
  __shared__ __align__(16) bf16_t As[5][128 * 32];
  __shared__ __align__(16) bf16_t Bs[5][128 * 32];

  const int z = blockIdx.z;
  const bf16_t* Bt = Btall + (size_t)z * Bz;
  const float* bias = biasAll + (size_t)z * biasz;
  OUT_T* C = Call + (size_t)z * Cz;

  const int tid = threadIdx.x;
  const int lane = tid & 63, wave = tid >> 6;
  const int quad = lane >> 4, l16 = lane & 15;
  const int swl = SW32(l16);
  const int wr = wave >> 1, wc = wave & 1;
  const int m0 = blockIdx.y * 128, n0 = blockIdx.x * 128;

  // staging slot swizzle: lane covers LDS slot (lane&3) of row arow (and arow+64);
  // fetch logical col (slot ^ SW32(arow)). SW32 invariant under +64.
  const int arow = wave * 16 + (lane >> 2);
  const int akc = (((lane & 3) ^ SW32(arow)) & 3) * 8;
  const bf16_t* gB0 = Bt + (size_t)(n0 + arow) * K + akc;
  const bf16_t* gB1 = gB0 + (size_t)64 * K;
  const bf16_t* A = Aall + (size_t)z * Az;
  const bf16_t* gA0 = A + (size_t)(m0 + arow) * K + akc;
  const bf16_t* gA1 = gA0 + (size_t)64 * K;

#define STAGEQ(t, buf)                               \
  do {                                               \
    const int k0_ = (t) * 32;                        \
    async16(gA0 + k0_, As[buf] + wave * 512);        \
    async16(gA1 + k0_, As[buf] + 2048 + wave * 512); \
    async16(gB0 + k0_, Bs[buf] + wave * 512);        \
    async16(gB1 + k0_, Bs[buf] + 2048 + wave * 512); \
  } while (0)

  const int nk = K / 32;
  STAGEQ(0, 0);
  STAGEQ(1, 1);
  STAGEQ(2, 2);

  f32x4 acc[4][4] = {};

  for (int it = 0; it < nk; ++it) {
    if (it + 3 < nk) STAGEQ(it + 3, (it + 3) % 5);

    if (it + 3 < nk)      WBAR(12);
    else if (it + 2 < nk) WBAR(8);
    else if (it + 1 < nk) WBAR(4);
    else                  WBAR(0);

    const bf16_t* Ac = As[it % 5];
    const bf16_t* Bc = Bs[it % 5];
    bf16x8 af[4], bfr[4];
#pragma unroll
    for (int i = 0; i < 4; ++i)
      af[i] = *(const bf16x8*)(Ac + (wr * 64 + i * 16 + l16) * 32 + ((quad ^ swl) & 3) * 8);
#pragma unroll
    for (int i = 0; i < 4; ++i)
      bfr[i] = *(const bf16x8*)(Bc + (wc * 64 + i * 16 + l16) * 32 + ((quad ^ swl) & 3) * 8);
#pragma unroll
    for (int mi = 0; mi < 4; ++mi)
#pragma unroll
      for (int ni = 0; ni < 4; ++ni)
        acc[mi][ni] = __builtin_amdgcn_mfma_f32_16x16x32_bf16(af[mi], bfr[ni], acc[mi][ni], 0, 0, 0);
  }
#undef STAGEQ

  if (EPI == 1 && z == 2) {
    // transposed masked write: V^T[(b*NH+h)*64+d][s] = (acc + bias) * mask[s]
#pragma unroll
    for (int mi = 0; mi < 4; ++mi) {
      const int rbase = m0 + wr * 64 + mi * 16 + quad * 4;
      const int bb = rbase >> 11, s = rbase & 2047;
      float rmv[4];
#pragma unroll
      for (int r = 0; r < 4; ++r) rmv[r] = rowmul[rbase + r];
#pragma unroll
      for (int ni = 0; ni < 4; ++ni) {
        const int col = n0 + wc * 64 + ni * 16 + l16;
        const float bv = bias[col];
        const int hh = col >> 6, d = col & 63;
        union { bf16_t e[4]; uint32x2 u; } p;
#pragma unroll
        for (int r = 0; r < 4; ++r) p.e[r] = (bf16_t)((acc[mi][ni][r] + bv) * rmv[r]);
        *(uint32x2*)(C2 + (((size_t)((bb * NH + hh) * DKc + d)) << 11) + s) = p.u;
      }
    }
    return;
  }

  const float scale = (EPI == 1 && z == 0) ? QSCALE : 1.f;
#pragma unroll
  for (int mi = 0; mi < 4; ++mi) {
    const int rbase = m0 + wr * 64 + mi * 16 + quad * 4;
#pragma unroll
    for (int ni = 0; ni < 4; ++ni) {
      const int col = n0 + wc * 64 + ni * 16 + l16;
      const float bv = bias[col];
#pragma unroll
      for (int r = 0; r < 4; ++r) {
        float y = (acc[mi][ni][r] + bv) * scale;
        C[(size_t)(rbase + r) * N + col] = (OUT_T)y;
      }
    }
  }
}

// ---------------- proj-o GEMM: 64x64 tile, 4 waves (wave = 16-row strip), ring-5 D=3 ----------------
// SW32-swizzled A and B tiles. WBAR(6/4/2/0), grid 512 -> 2 blocks/CU.
__global__ __launch_bounds__(256, 2) void k_gemmO(const bf16_t* __restrict__ A,
                                                  const bf16_t* __restrict__ Bt,
                                                  const float* __restrict__ bias,
                                                  bf16_t* __restrict__ C) {
  __shared__ __align__(16) bf16_t As[5][64 * 32];
  __shared__ __align__(16) bf16_t Bs[5][64 * 32];

  const int tid = threadIdx.x;
  const int lane = tid & 63, wave = tid >> 6; // 0..3
  const int quad = lane >> 4, l16 = lane & 15;
  const int swl = SW32(l16);
  const int m0 = blockIdx.y * 64, n0 = blockIdx.x * 64;

  const int srow = wave * 16 + (lane >> 2);
  const int skc = (((lane & 3) ^ SW32(srow)) & 3) * 8;
  const bf16_t* gA0 = A + (size_t)(m0 + srow) * HID + skc;
  const bf16_t* gB0 = Bt + (size_t)(n0 + srow) * HID + skc;

#define STAGEO(t, buf)                                 \
  do {                                                 \
    const int k0_ = (t) * 32;                          \
    async16(gA0 + k0_, As[buf] + wave * 512);          \
    async16(gB0 + k0_, Bs[buf] + wave * 512);          \
  } while (0)

  constexpr int nk = HID / 32; // 32
  STAGEO(0, 0);
  STAGEO(1, 1);
  STAGEO(2, 2);

  f32x4 acc[4] = {};

  for (int it = 0; it < nk; ++it) {
    if (it + 3 < nk) STAGEO(it + 3, (it + 3) % 5);

    if (it + 3 < nk)      WBAR(6);
    else if (it + 2 < nk) WBAR(4);
    else if (it + 1 < nk) WBAR(2);
    else                  WBAR(0);

    const bf16_t* Ac = As[it % 5];
    const bf16_t* Bc = Bs[it % 5];
    bf16x8 af = *(const bf16x8*)(Ac + (wave * 16 + l16) * 32 + ((quad ^ swl) & 3) * 8);
    bf16x8 bfr[4];
#pragma unroll
    for (int i = 0; i < 4; ++i)
      bfr[i] = *(const bf16x8*)(Bc + (i * 16 + l16) * 32 + ((quad ^ swl) & 3) * 8);
#pragma unroll
    for (int ni = 0; ni < 4; ++ni)
      acc[ni] = __builtin_amdgcn_mfma_f32_16x16x32_bf16(af, bfr[ni], acc[ni], 0, 0, 0);
  }
#undef STAGEO

  const int rbase = m0 + wave * 16 + quad * 4;
#pragma unroll
  for (int ni = 0; ni < 4; ++ni) {
    const int col = n0 + ni * 16 + l16;
    const float bv = bias[col];
#pragma unroll
    for (int r = 0; r < 4; ++r) {
      float y = acc[ni][r] + bv;
      y = (y > 0.f) ? y : 0.2f * y;
      C[(size_t)(rbase + r) * FAC + col] = (bf16_t)y;
    }
  }
}

// ---------------- flash attention v9 (R5 exact): 512 q-rows/block, 8 waves x 4 q-groups ----------------
__global__ __launch_bounds__(512, 2) void k_attn(const bf16_t* __restrict__ qkv,
                                                 const bf16_t* __restrict__ mb,
                                                 bf16_t* __restrict__ cv) {
  __shared__ __align__(16) bf16_t Ks[4][64 * 64];
  __shared__ __align__(16) bf16_t Vt[4][64 * 64];
  __shared__ __align__(16) bf16_t Ml[Ssz];

  const int qt = blockIdx.x, h = blockIdx.y, b = blockIdx.z;
  const bf16_t* qp = qkv;
  const bf16_t* kp = qkv + (size_t)Mrows * HID;
  const bf16_t* vtp = qkv + 2 * (size_t)Mrows * HID + (size_t)(b * NH + h) * DKc * Ssz;

  const int tid = threadIdx.x;
  const int lane = tid & 63, wave = tid >> 6;   // wave 0..7
  const int quad = lane >> 4, l16 = lane & 15;

  // staging: each of 8 waves stages 8 rows of K and 8 rows of V^T (1024 B each)
  const int r0 = wave * 8 + (lane >> 3);
  const int c0 = ((lane & 7) ^ SW(r0)) * 8;
  const int ldsOff = wave * 512; // elements (1024 B per wave)
  const bf16_t* kgA = kp + (size_t)(b * Ssz + r0) * HID + h * DKc + c0;
  const bf16_t* vgA = vtp + (size_t)r0 * Ssz + c0;

#define STAGEA(t, buf)                                          \
  do {                                                          \
    async16(kgA + (size_t)(t) * 64 * HID, Ks[buf] + ldsOff);    \
    async16(vgA + (t) * 64, Vt[buf] + ldsOff);                  \
  } while (0)

  *(uint32x2*)(Ml + tid * 4) = *(const uint32x2*)(mb + (size_t)b * Ssz + tid * 4);
  STAGEA(0, 0);
  STAGEA(1, 1);

  // 4 q-groups of 16 rows per wave: rows qt*512 + g*128 + wave*16 + l16
  bf16x8 aq0[4], aq1[4];
#pragma unroll
  for (int g = 0; g < 4; ++g) {
    const size_t qrow = (size_t)(b * Ssz + qt * 512 + g * 128 + wave * 16 + l16) * HID + h * DKc + quad * 8;
    aq0[g] = *(const bf16x8*)(qp + qrow);
    aq1[g] = *(const bf16x8*)(qp + qrow + 32);
  }

  const int krow = 8 * (l16 >> 2) + (l16 & 3);
  f32x4 acc[4][4] = {};
  f32x4 dacc[4] = {};
  const bf16x8 zfrag = {};

  for (int kt = 0; kt < 32; ++kt) {
    if (kt + 2 < 32) STAGEA(kt + 2, (kt + 2) & 3);

    if (kt + 2 < 32)      WBAR(4);
    else if (kt + 1 < 32) WBAR(2);
    else                  WBAR(0);

    const bf16_t* Kc = Ks[kt & 3];
    const bf16_t* Vc = Vt[kt & 3];

    union U { uint32x4 u; bf16x8 h; } ap0[4], ap1[4];
    constexpr int koff[4] = {0, 4, 32, 36};
#pragma unroll
    for (int ks = 0; ks < 4; ++ks) {
      const int row = krow + koff[ks];
      const int sw = SW(row);
      bf16x8 a0 = *(const bf16x8*)(Kc + row * 64 + (quad ^ sw) * 8);
      bf16x8 a1 = *(const bf16x8*)(Kc + row * 64 + ((quad + 4) ^ sw) * 8);
#pragma unroll
      for (int g = 0; g < 4; ++g) {
        f32x4 c = {};
        c = __builtin_amdgcn_mfma_f32_16x16x32_bf16(a0, aq0[g], c, 0, 0, 0);
        c = __builtin_amdgcn_mfma_f32_16x16x32_bf16(a1, aq1[g], c, 0, 0, 0);
        union { bf16_t h[2]; uint32_t u; } p01, p23;
        p01.h[0] = (bf16_t)fast_exp2(c[0]);
        p01.h[1] = (bf16_t)fast_exp2(c[1]);
        p23.h[0] = (bf16_t)fast_exp2(c[2]);
        p23.h[1] = (bf16_t)fast_exp2(c[3]);
        U& t = (ks < 2) ? ap0[g] : ap1[g];
        t.u[(ks & 1) * 2] = p01.u;
        t.u[(ks & 1) * 2 + 1] = p23.u;
      }
    }

    bf16x8 mr0 = *(const bf16x8*)(Ml + kt * 64 + quad * 8);
    bf16x8 mr1 = *(const bf16x8*)(Ml + kt * 64 + 32 + quad * 8);
    if (l16 != 0) { mr0 = zfrag; mr1 = zfrag; }
#pragma unroll
    for (int g = 0; g < 4; ++g) {
      dacc[g] = __builtin_amdgcn_mfma_f32_16x16x32_bf16(ap0[g].h, mr0, dacc[g], 0, 0, 0);
      dacc[g] = __builtin_amdgcn_mfma_f32_16x16x32_bf16(ap1[g].h, mr1, dacc[g], 0, 0, 0);
    }

#pragma unroll
    for (int d = 0; d < 4; ++d) {
      const int row = d * 16 + l16;
      const int sw = SW(row);
      bf16x8 bv0 = *(const bf16x8*)(Vc + row * 64 + (quad ^ sw) * 8);
      bf16x8 bv1 = *(const bf16x8*)(Vc + row * 64 + ((quad + 4) ^ sw) * 8);
#pragma unroll
      for (int g = 0; g < 4; ++g) {
        acc[g][d] = __builtin_amdgcn_mfma_f32_16x16x32_bf16(ap0[g].h, bv0, acc[g][d], 0, 0, 0);
        acc[g][d] = __builtin_amdgcn_mfma_f32_16x16x32_bf16(ap1[g].h, bv1, acc[g][d], 0, 0, 0);
      }
    }
  }
#undef STAGEA

#pragma unroll
  for (int g = 0; g < 4; ++g) {
    const size_t obase = (size_t)(b * Ssz + qt * 512 + g * 128 + wave * 16 + quad * 4) * HID + h * DKc + l16;
#pragma unroll
    for (int r = 0; r < 4; ++r) {
      const float denom = __shfl(dacc[g][r], lane & 48, 64);
      const float rl = 1.f / denom;
#pragma unroll
      for (int d = 0; d < 4; ++d)
        cv[obase + (size_t)r * HID + d * 16] = (bf16_t)(acc[g][d][r] * rl);
    }
  }
}

// ---------------- host ----------------
extern "C" void kernel_launch(void* const* d_in, const int* in_sizes, int n_in,
                              void* d_out, int out_size, void* d_ws, size_t ws_size,
                              hipStream_t stream) {
  (void)in_sizes; (void)n_in; (void)out_size; (void)ws_size;
  const float* q_in = (const float*)d_in[0];
  const float* k_in = (const float*)d_in[1];
  const float* v_in = (const float*)d_in[2];
  const int* mask = (const int*)d_in[3];

  bf16_t* XB = (bf16_t*)d_ws;                          // 3 slots [8192,1024] bf16: q, k, V^T
  bf16_t* H3 = XB + (size_t)3 * Mrows * HID;           // 3 x [8192,256] bf16
  bf16_t* CV = H3 + (size_t)3 * Mrows * FAC;           // [8192,1024] bf16 (attn out)
  bf16_t* WPT = CV + (size_t)Mrows * HID;              // 4 x [256,1024] bf16
  bf16_t* WTT = WPT + (size_t)4 * FAC * HID;           // 4 x [1024,256] bf16
  float* BP = (float*)(WTT + (size_t)4 * FAC * HID);   // 4 x 256 f32
  float* BT = BP + 4 * FAC;                            // 4 x 1024 f32
  float* MF = BT + 4 * HID;                            // [8192] f32 mask rowmul
  bf16_t* MB = (bf16_t*)(MF + Mrows);                  // [8192] bf16 mask row
  bf16_t* VTg = XB + 2 * (size_t)Mrows * HID;          // V^T slot

  Ptr8 w;
  w.p[0] = (const float*)d_in[4];  w.p[1] = (const float*)d_in[8];
  w.p[2] = (const float*)d_in[12]; w.p[3] = (const float*)d_in[16];
  w.p[4] = (const float*)d_in[6];  w.p[5] = (const float*)d_in[10];
  w.p[6] = (const float*)d_in[14]; w.p[7] = (const float*)d_in[18];
  Ptr8 bs;
  bs.p[0] = (const float*)d_in[5];  bs.p[1] = (const float*)d_in[9];
  bs.p[2] = (const float*)d_in[13]; bs.p[3] = (const float*)d_in[17];
  bs.p[4] = (const float*)d_in[7];  bs.p[5] = (const float*)d_in[11];
  bs.p[6] = (const float*)d_in[15]; bs.p[7] = (const float*)d_in[19];
  hipLaunchKernelGGL(k_prep, dim3(256, 1, 9), dim3(256), 0, stream, w, bs, mask,
                     WPT, WTT, BP, BT, MF, MB);

  Ptr3 xs; xs.p[0] = q_in; xs.p[1] = k_in; xs.p[2] = v_in;

  // proj q,k,v: fp32 A (cast fused) @ WPT^T + b -> leaky -> H3 [3 blocks/CU, B swizzled]
  hipLaunchKernelGGL(k_gemmP2, dim3(2, Mrows / 64, 3), dim3(256), 0, stream,
                     xs, WPT, BP, H3);

  // tran q,k,v: H3 @ WTT^T + b -> q(scaled),k into XB; v masked+TRANSPOSED into VTg [swizzled]
  hipLaunchKernelGGL((k_gemmQ<1, bf16_t>), dim3(HID / 128, Mrows / 128, 3), dim3(256), 0, stream,
                     H3, WTT, BT, XB, VTg, MF,
                     HID, FAC, (long long)Mrows * FAC, (long long)FAC * HID, (long long)Mrows * HID, HID);

  // attention -> CV (512 q-rows per block, 8 waves x 4 groups, 256 blocks)
  hipLaunchKernelGGL(k_attn, dim3(Ssz / 512, NH, Bsz), dim3(512), 0, stream, XB, MB, CV);

  // proj o: CV @ WPT[o]^T + b -> leaky -> H3[0]  [512 blocks, 4-wave 64x64, swizzled]
  hipLaunchKernelGGL(k_gemmO, dim3(FAC / 64, Mrows / 64, 1), dim3(256), 0, stream,
                     CV, WPT + (size_t)3 * FAC * HID, BP + 3 * FAC, H3);

  // tran o: H3 @ WTT[o]^T + b -> d_out (fp32)  [512 blocks, swizzled]
  hipLaunchKernelGGL((k_gemmQ<2, float>), dim3(HID / 128, Mrows / 128, 1), dim3(256), 0, stream,
                     H3, WTT + (size_t)3 * FAC * HID, BT + 3 * HID, (float*)d_out, (bf16_t*)nullptr,
                     (const float*)nullptr, HID, FAC, 0LL, 0LL, 0LL, 0);
}